// Round 1
// baseline (282.807 us; speedup 1.0000x reference)
//
#include <hip/hip_runtime.h>

#define NTH 256
#define TT 2048

// LDS: two ping-pong complex buffers + 512-entry twiddle table + reduction pad.
// 2*2048*8 + 512*8 + 16 = 36880 B -> 4 blocks/CU (147.5 KB of 160 KB).
struct SMem {
  float2 A[TT];
  float2 B[TT];
  float2 tw[512];
  float red[4];
};

// Bank swizzle: XOR bits[3:0] pattern with ((idx>>4)&3)*5 (i.e. bits 0-1 and 2-3).
// Makes both the Stockham strided reads (stride 512) and the s=1 / s=4 stage
// writes (idx = 4j+r etc.) uniform over 16 bank-pairs per 16-lane group.
__device__ __forceinline__ int swz(int i) { return i ^ (((i >> 4) & 3) * 5); }

__device__ __forceinline__ float2 cmul(float2 a, float2 b) {
  return make_float2(a.x * b.x - a.y * b.y, a.x * b.y + a.y * b.x);
}

__device__ __forceinline__ void init_tw(SMem& sm) {
  // tw[k] = exp(-i*pi*k/1024) = e^{-2*pi*i*k/2048}, k in [0,512)
#pragma unroll
  for (int i = 0; i < 2; ++i) {
    const int k = (int)threadIdx.x + NTH * i;
    float s, c;
    sincosf(-(3.14159265358979323846f / 1024.0f) * (float)k, &s, &c);
    sm.tw[k] = make_float2(c, s);
  }
}

// 2048-pt complex FFT, Stockham autosort: 5 radix-4 stages + 1 radix-2 stage.
// Input in sm.A, output in sm.A. INV=false: sum x_j e^{-2pi i jk/N} (forward).
// INV=true : sum x_j e^{+2pi i jk/N} (unnormalized inverse; scale by 1/N later).
// Caller need not sync before call (first stage syncs); trailing sync included.
template <bool INV>
__device__ __forceinline__ void fft2048(SMem& sm) {
  const float sgn = INV ? -1.0f : 1.0f;
  float2* cur = sm.A;
  float2* oth = sm.B;
#pragma unroll
  for (int logs = 0; logs <= 8; logs += 2) {
    const int s = 1 << logs;
    __syncthreads();
#pragma unroll
    for (int i = 0; i < 2; ++i) {
      const int j = (int)threadIdx.x + NTH * i;  // 0..511; m*s == 512 invariant
      const float2 a = cur[swz(j)];
      const float2 b = cur[swz(j + 512)];
      const float2 c = cur[swz(j + 1024)];
      const float2 d = cur[swz(j + 1536)];
      float2 w1 = sm.tw[j & ~(s - 1)];  // tw[p << logs], p = j>>logs
      if (INV) w1.y = -w1.y;
      const float2 w2 = cmul(w1, w1);
      const float2 w3 = cmul(w2, w1);
      const float t0x = a.x + c.x, t0y = a.y + c.y;
      const float t1x = a.x - c.x, t1y = a.y - c.y;
      const float t2x = b.x + d.x, t2y = b.y + d.y;
      const float bdx = b.x - d.x, bdy = b.y - d.y;
      // fwd: t3 = -i*(b-d) = (bdy, -bdx); inv: t3 = +i*(b-d) = (-bdy, bdx)
      const float t3x = sgn * bdy, t3y = -sgn * bdx;
      const int wb = (j & (s - 1)) + ((j >> logs) << (logs + 2));
      oth[swz(wb)]         = make_float2(t0x + t2x, t0y + t2y);
      oth[swz(wb + s)]     = cmul(w1, make_float2(t1x + t3x, t1y + t3y));
      oth[swz(wb + 2 * s)] = cmul(w2, make_float2(t0x - t2x, t0y - t2y));
      oth[swz(wb + 3 * s)] = cmul(w3, make_float2(t1x - t3x, t1y - t3y));
    }
    float2* t = cur; cur = oth; oth = t;
  }
  // final radix-2 stage (s=1024, twiddle = 1); cur==sm.B here, writes sm.A.
  __syncthreads();
#pragma unroll
  for (int i = 0; i < 4; ++i) {
    const int j = (int)threadIdx.x + NTH * i;  // 0..1023
    const float2 a = cur[swz(j)];
    const float2 b = cur[swz(j + 1024)];
    oth[swz(j)]        = make_float2(a.x + b.x, a.y + b.y);
    oth[swz(j + 1024)] = make_float2(a.x - b.x, a.y - b.y);
  }
  __syncthreads();
}

// sm.A holds Uh = fft(U) (U real, unnormalized). phi is ~zero beyond bin 4:
// phi_f = exp(-1.2207*f^2); phi5=5.6e-14. s_t = (1/N)(Uh0 + 2*sum_f phi_f Re(Uh_f e^{+i 2pi f t/N})).
// Computes mean_t log(s_t + 1e-6) over the block, writes single float to outp.
__device__ __forceinline__ void smooth_log_out(SMem& sm, float* outp) {
  const float phi1 = __expf(-1.220703125f);
  const float phi2 = __expf(-4.8828125f);
  const float phi3 = __expf(-10.986328125f);
  const float phi4 = __expf(-19.53125f);
  // swz(0..4) == identity (idx < 16)
  const float  c0 = sm.A[0].x * (1.0f / 2048.0f);
  const float2 U1 = sm.A[1];
  const float2 U2 = sm.A[2];
  const float2 U3 = sm.A[3];
  const float2 U4 = sm.A[4];
  const float k1 = phi1 * (2.0f / 2048.0f);
  const float k2 = phi2 * (2.0f / 2048.0f);
  const float k3 = phi3 * (2.0f / 2048.0f);
  const float k4 = phi4 * (2.0f / 2048.0f);
  float part = 0.0f;
#pragma unroll
  for (int i = 0; i < 8; ++i) {
    const int t = (int)threadIdx.x + NTH * i;
    float sv, cv;
    __sincosf((6.283185307179586f / 2048.0f) * (float)t, &sv, &cv);
    float acc = c0 + k1 * (U1.x * cv - U1.y * sv);
    const float c2v = cv * cv - sv * sv, s2v = 2.0f * sv * cv;
    acc += k2 * (U2.x * c2v - U2.y * s2v);
    const float c3v = c2v * cv - s2v * sv, s3v = s2v * cv + c2v * sv;
    acc += k3 * (U3.x * c3v - U3.y * s3v);
    const float c4v = c3v * cv - s3v * sv, s4v = s3v * cv + c3v * sv;
    acc += k4 * (U4.x * c4v - U4.y * s4v);
    part += __logf(acc + 1e-6f);
  }
#pragma unroll
  for (int off = 32; off > 0; off >>= 1) part += __shfl_down(part, off, 64);
  const int lane = (int)threadIdx.x & 63, wid = (int)threadIdx.x >> 6;
  if (lane == 0) sm.red[wid] = part;
  __syncthreads();
  if (threadIdx.x == 0)
    *outp = (sm.red[0] + sm.red[1] + sm.red[2] + sm.red[3]) * (1.0f / 2048.0f);
}

// Stage A: xh[n] = fft(x[n]) for the 48 folded signals (n = b*6 + c).
__global__ __launch_bounds__(NTH) void kA(const float* __restrict__ x,
                                          float2* __restrict__ xh) {
  __shared__ SMem sm;
  init_tw(sm);
  const int n = blockIdx.x;
  const int b = n / 6, c = n % 6;
  const float* xp = x + (size_t)b * (TT * 6) + c;
#pragma unroll
  for (int i = 0; i < 8; ++i) {
    const int t = (int)threadIdx.x + NTH * i;
    sm.A[swz(t)] = make_float2(xp[t * 6], 0.0f);
  }
  fft2048<false>(sm);
#pragma unroll
  for (int i = 0; i < 8; ++i) {
    const int t = (int)threadIdx.x + NTH * i;
    xh[(size_t)n * TT + t] = sm.A[swz(t)];
  }
}

// Loads src spectrum * Gaussian(xi,sig), ifft, |.|/N back into sm.A (imag=0).
__device__ __forceinline__ void band_envelope(SMem& sm, const float2* __restrict__ src,
                                              float xi, float sig) {
  const float inv2s2 = 1.0f / (2.0f * sig * sig);
#pragma unroll
  for (int i = 0; i < 8; ++i) {
    const int f = (int)threadIdx.x + NTH * i;
    const float fr = (float)(f < 1024 ? f : f - 2048) * (1.0f / 2048.0f);
    const float d = fr - xi;
    const float g = __expf(-d * d * inv2s2);
    const float2 v = src[f];
    sm.A[swz(f)] = make_float2(v.x * g, v.y * g);
  }
  fft2048<true>(sm);  // unnormalized inverse
#pragma unroll
  for (int i = 0; i < 8; ++i) {
    const int f = (int)threadIdx.x + NTH * i;
    const float2 v = sm.A[swz(f)];
    const float m = sqrtf(v.x * v.x + v.y * v.y) * (1.0f / 2048.0f);
    sm.A[swz(f)] = make_float2(m, 0.0f);
  }
  // next fft2048 syncs before reading
}

// Stage B: per (n, j1): U1h = fft(|ifft(xh*psi1)|); store U1h; S1 log-mean out.
__global__ __launch_bounds__(NTH) void kB(const float2* __restrict__ xh,
                                          float2* __restrict__ U1h,
                                          float* __restrict__ out) {
  __shared__ SMem sm;
  init_tw(sm);
  const int blk = blockIdx.x;       // n*80 + j1 (n-major: xh reuse in L2)
  const int n = blk / 80, j1 = blk % 80;
  const float xi = 0.4f * exp2f(-0.125f * (float)j1);
  band_envelope(sm, xh + (size_t)n * TT, xi, 0.1f * xi);  // sig1 = 0.8*xi/8
  fft2048<false>(sm);               // sm.A = U1h
  float2* dst = U1h + (size_t)blk * TT;
#pragma unroll
  for (int i = 0; i < 8; ++i) {
    const int f = (int)threadIdx.x + NTH * i;
    dst[f] = sm.A[swz(f)];
  }
  const int b = n / 6, c = n % 6;
  smooth_log_out(sm, out + ((size_t)b * 440 + j1) * 6 + c);
}

// Stage C: per (n, p): S2 for pair p -> (k, j1), j1 = p - 4k(k-1).
__global__ __launch_bounds__(NTH) void kC(const float2* __restrict__ U1h,
                                          float* __restrict__ out) {
  __shared__ SMem sm;
  init_tw(sm);
  const int blk = blockIdx.x;       // n*360 + p
  const int n = blk / 360, p = blk % 360;
  int k = 1;
  while (k < 9 && p >= 4 * k * (k + 1)) ++k;   // off(k) = 4k(k-1), len 8k
  const int j1 = p - 4 * k * (k - 1);
  const float xi = 0.4f * exp2f(-(float)k);
  band_envelope(sm, U1h + ((size_t)n * 80 + j1) * TT, xi, 0.8f * xi);
  fft2048<false>(sm);               // sm.A = U2h
  const int b = n / 6, c = n % 6;
  smooth_log_out(sm, out + ((size_t)b * 440 + 80 + p) * 6 + c);
}

// Fallback (small ws): fused B+C; U1h kept in 16 VGPRs/thread, only xh in ws.
__global__ __launch_bounds__(NTH) void kBC(const float2* __restrict__ xh,
                                           float* __restrict__ out) {
  __shared__ SMem sm;
  init_tw(sm);
  const int blk = blockIdx.x;
  const int n = blk / 80, j1 = blk % 80;
  const int b = n / 6, c = n % 6;
  const float xi = 0.4f * exp2f(-0.125f * (float)j1);
  band_envelope(sm, xh + (size_t)n * TT, xi, 0.1f * xi);
  fft2048<false>(sm);
  float2 uh[8];
#pragma unroll
  for (int i = 0; i < 8; ++i) uh[i] = sm.A[swz((int)threadIdx.x + NTH * i)];
  smooth_log_out(sm, out + ((size_t)b * 440 + j1) * 6 + c);
  const int o = j1 >> 3;
  for (int k = o + 1; k <= 9; ++k) {
    const int p = 4 * k * (k - 1) + j1;
    const float xi2 = 0.4f * exp2f(-(float)k);
    const float sg2 = 0.8f * xi2;
    const float i2s2 = 1.0f / (2.0f * sg2 * sg2);
    __syncthreads();
#pragma unroll
    for (int i = 0; i < 8; ++i) {
      const int f = (int)threadIdx.x + NTH * i;
      const float fr = (float)(f < 1024 ? f : f - 2048) * (1.0f / 2048.0f);
      const float d = fr - xi2;
      const float g = __expf(-d * d * i2s2);
      sm.A[swz(f)] = make_float2(uh[i].x * g, uh[i].y * g);
    }
    fft2048<true>(sm);
#pragma unroll
    for (int i = 0; i < 8; ++i) {
      const int f = (int)threadIdx.x + NTH * i;
      const float2 v = sm.A[swz(f)];
      const float m = sqrtf(v.x * v.x + v.y * v.y) * (1.0f / 2048.0f);
      sm.A[swz(f)] = make_float2(m, 0.0f);
    }
    fft2048<false>(sm);
    smooth_log_out(sm, out + ((size_t)b * 440 + 80 + p) * 6 + c);
  }
}

extern "C" void kernel_launch(void* const* d_in, const int* in_sizes, int n_in,
                              void* d_out, int out_size, void* d_ws, size_t ws_size,
                              hipStream_t stream) {
  (void)in_sizes; (void)n_in; (void)out_size;
  const float* x = (const float*)d_in[0];   // [8, 2048, 6] fp32
  float* out = (float*)d_out;               // [8, 440, 6] fp32
  const size_t U1H_BYTES = (size_t)48 * 80 * TT * sizeof(float2);  // 62.9 MB
  const size_t XH_BYTES  = (size_t)48 * TT * sizeof(float2);       // 786 KB
  if (ws_size >= U1H_BYTES + XH_BYTES) {
    float2* U1h = (float2*)d_ws;
    float2* xh  = (float2*)((char*)d_ws + U1H_BYTES);
    kA<<<dim3(48),    dim3(NTH), 0, stream>>>(x, xh);
    kB<<<dim3(3840),  dim3(NTH), 0, stream>>>(xh, U1h, out);
    kC<<<dim3(17280), dim3(NTH), 0, stream>>>(U1h, out);
  } else {
    float2* xh = (float2*)d_ws;
    kA<<<dim3(48),   dim3(NTH), 0, stream>>>(x, xh);
    kBC<<<dim3(3840), dim3(NTH), 0, stream>>>(xh, out);
  }
}

// Round 2
// 193.535 us; speedup vs baseline: 1.4613x; 1.4613x over previous
//
#include <hip/hip_runtime.h>

#define NTH 256
#define TT 2048

// LDS: ping-pong complex buffers + 512-entry twiddle table + reduction pads.
// 16384+16384+4096+16+144 = 37024 B -> 4 blocks/CU.
struct SMem {
  float2 A[TT];
  float2 B[TT];
  float2 tw[512];
  float red[4];
  float binred[4][9];
};

// Bank swizzle (round-1 measured: 0 LDS bank conflicts).
__device__ __forceinline__ int swz(int i) { return i ^ (((i >> 4) & 3) * 5); }

__device__ __forceinline__ float2 cmul(float2 a, float2 b) {
  return make_float2(a.x * b.x - a.y * b.y, a.x * b.y + a.y * b.x);
}

__device__ __forceinline__ float wave_sum(float v) {
#pragma unroll
  for (int off = 32; off > 0; off >>= 1) v += __shfl_down(v, off, 64);
  return v;
}

__device__ __forceinline__ void init_tw(SMem& sm) {
  // tw[k] = e^{-2*pi*i*k/2048}, k in [0,512)
#pragma unroll
  for (int i = 0; i < 2; ++i) {
    const int k = (int)threadIdx.x + NTH * i;
    float s, c;
    sincosf(-(3.14159265358979323846f / 1024.0f) * (float)k, &s, &c);
    sm.tw[k] = make_float2(c, s);
  }
}

// M-point Stockham FFT (M in {256,512,1024,2048}), input sm.A, returns output
// buffer pointer (sm.A or sm.B). INV=false: e^{-}, INV=true: unnormalized e^{+}.
// Twiddles sampled from the 2048-table at stride R=2048/M.
template <int M, bool INV>
__device__ __forceinline__ float2* fftM(SMem& sm) {
  constexpr int R = 2048 / M;
  constexpr int NQ = M / 4;                                // butterflies/stage
  constexpr int NR4 = (M == 2048 || M == 1024) ? 5 : 4;    // radix-4 stages
  constexpr bool HASR2 = (M == 2048 || M == 512);
  const float sgn = INV ? -1.0f : 1.0f;
  float2* cur = sm.A;
  float2* oth = sm.B;
#pragma unroll
  for (int st = 0; st < NR4; ++st) {
    const int logs = 2 * st;
    const int s = 1 << logs;
    __syncthreads();
#pragma unroll
    for (int i = 0; i < (NQ + NTH - 1) / NTH; ++i) {
      const int j = (int)threadIdx.x + NTH * i;
      if (NQ < NTH && j >= NQ) break;
      const float2 a = cur[swz(j)];
      const float2 b = cur[swz(j + NQ)];
      const float2 c = cur[swz(j + 2 * NQ)];
      const float2 d = cur[swz(j + 3 * NQ)];
      float2 w1 = sm.tw[(j & ~(s - 1)) * R];
      if (INV) w1.y = -w1.y;
      const float2 w2 = cmul(w1, w1);
      const float2 w3 = cmul(w2, w1);
      const float t0x = a.x + c.x, t0y = a.y + c.y;
      const float t1x = a.x - c.x, t1y = a.y - c.y;
      const float t2x = b.x + d.x, t2y = b.y + d.y;
      const float bdx = b.x - d.x, bdy = b.y - d.y;
      const float t3x = sgn * bdy, t3y = -sgn * bdx;  // -i*(b-d) fwd, +i inv
      const int wb = (j & (s - 1)) + ((j >> logs) << (logs + 2));
      oth[swz(wb)]         = make_float2(t0x + t2x, t0y + t2y);
      oth[swz(wb + s)]     = cmul(w1, make_float2(t1x + t3x, t1y + t3y));
      oth[swz(wb + 2 * s)] = cmul(w2, make_float2(t0x - t2x, t0y - t2y));
      oth[swz(wb + 3 * s)] = cmul(w3, make_float2(t1x - t3x, t1y - t3y));
    }
    float2* t = cur; cur = oth; oth = t;
  }
  if (HASR2) {
    __syncthreads();
#pragma unroll
    for (int i = 0; i < (M / 2 + NTH - 1) / NTH; ++i) {
      const int j = (int)threadIdx.x + NTH * i;
      if (M / 2 < NTH && j >= M / 2) break;
      const float2 a = cur[swz(j)];
      const float2 b = cur[swz(j + M / 2)];
      oth[swz(j)]         = make_float2(a.x + b.x, a.y + b.y);
      oth[swz(j + M / 2)] = make_float2(a.x - b.x, a.y - b.y);
    }
    float2* t = cur; cur = oth; oth = t;
  }
  __syncthreads();
  return cur;
}

// P holds M-point forward-DFT bins of the (real) smoothed-input signal.
// s_t = (1/M)(B0 + 2*sum_{f=1..4} phi_f Re(B_f e^{+2pi i f t/M})); phi_f at
// true freq f/2048 (phi is ~zero beyond bin 4). Writes mean_t log(s_t+1e-6).
template <int M>
__device__ __forceinline__ void smooth_log_out(SMem& sm, const float2* __restrict__ P,
                                               float* outp) {
  const float phi1 = __expf(-1.220703125f);
  const float phi2 = __expf(-4.8828125f);
  const float phi3 = __expf(-10.986328125f);
  const float phi4 = __expf(-19.53125f);
  const float c0 = P[0].x * (1.0f / (float)M);  // swz(0..4)==identity
  const float2 U1 = P[1], U2 = P[2], U3 = P[3], U4 = P[4];
  const float k1 = phi1 * (2.0f / (float)M);
  const float k2 = phi2 * (2.0f / (float)M);
  const float k3 = phi3 * (2.0f / (float)M);
  const float k4 = phi4 * (2.0f / (float)M);
  float part = 0.0f;
#pragma unroll
  for (int i = 0; i < (M + NTH - 1) / NTH; ++i) {
    const int t = (int)threadIdx.x + NTH * i;
    if (M < NTH && t >= M) break;
    float sv, cv;
    __sincosf((6.283185307179586f / (float)M) * (float)t, &sv, &cv);
    float acc = c0 + k1 * (U1.x * cv - U1.y * sv);
    const float c2 = cv * cv - sv * sv, s2 = 2.0f * sv * cv;
    acc += k2 * (U2.x * c2 - U2.y * s2);
    const float c3 = c2 * cv - s2 * sv, s3 = s2 * cv + c2 * sv;
    acc += k3 * (U3.x * c3 - U3.y * s3);
    const float c4 = c3 * cv - s3 * sv, s4 = s3 * cv + c3 * sv;
    acc += k4 * (U4.x * c4 - U4.y * s4);
    part += __logf(acc + 1e-6f);
  }
  part = wave_sum(part);
  const int lane = (int)threadIdx.x & 63, wid = (int)threadIdx.x >> 6;
  if (lane == 0) sm.red[wid] = part;
  __syncthreads();
  if (threadIdx.x == 0)
    *outp = (sm.red[0] + sm.red[1] + sm.red[2] + sm.red[3]) * (1.0f / (float)M);
}

// U1h storage: per signal, j1<8: M1=2048; <16: 1024; <24: 512; else 256.
__device__ __forceinline__ int u1h_off(int j1) {
  const int o = j1 >> 3;
  if (o == 0) return j1 * 2048;
  if (o == 1) return 16384 + (j1 - 8) * 1024;
  if (o == 2) return 24576 + (j1 - 16) * 512;
  return 28672 + (j1 - 24) * 256;
}
#define U1H_STRIDE 43008  // 28672 + 56*256

// Stage A: xh[n] = fft2048(x[n]), n = b*6+c.
__global__ __launch_bounds__(NTH) void kA(const float* __restrict__ x,
                                          float2* __restrict__ xh) {
  __shared__ SMem sm;
  init_tw(sm);
  const int n = blockIdx.x;
  const int b = n / 6, c = n % 6;
  const float* xp = x + (size_t)b * (TT * 6) + c;
#pragma unroll
  for (int i = 0; i < 8; ++i) {
    const int t = (int)threadIdx.x + NTH * i;
    sm.A[swz(t)] = make_float2(xp[t * 6], 0.0f);
  }
  float2* P = fftM<TT, false>(sm);
#pragma unroll
  for (int i = 0; i < 8; ++i) {
    const int t = (int)threadIdx.x + NTH * i;
    xh[(size_t)n * TT + t] = P[swz(t)];
  }
}

// Stage B: per (n, j1): fold(xh*psi1) to M1, ifft_M1, |.|/2048 (exact
// subsampled U1), forward fft_M1 -> store V (== fold(U1h)*M1/2048), S1 out.
template <int M1>
__global__ __launch_bounds__(NTH) void kB(const float2* __restrict__ xh,
                                          float2* __restrict__ U1h,
                                          float* __restrict__ out,
                                          int j1_base, int cnt) {
  __shared__ SMem sm;
  init_tw(sm);
  const int n = (int)blockIdx.x / cnt;
  const int j1 = j1_base + (int)blockIdx.x % cnt;
  constexpr int R1 = 2048 / M1;
  const float xi = 0.4f * exp2f(-0.125f * (float)j1);
  const float sig = 0.1f * xi;  // 0.8*xi/Q, Q=8
  const float inv2s2 = 1.0f / (2.0f * sig * sig);
  const float2* src = xh + (size_t)n * TT;
#pragma unroll
  for (int i = 0; i < (M1 + NTH - 1) / NTH; ++i) {
    const int m = (int)threadIdx.x + NTH * i;
    if (M1 < NTH && m >= M1) break;
    float2 acc = make_float2(0.0f, 0.0f);
#pragma unroll
    for (int q = 0; q < R1; ++q) {
      const int f = m + q * M1;
      const float fr = (float)(f < 1024 ? f : f - 2048) * (1.0f / 2048.0f);
      const float d = fr - xi;
      const float g = __expf(-d * d * inv2s2);
      const float2 v = src[f];
      acc.x += v.x * g;
      acc.y += v.y * g;
    }
    sm.A[swz(m)] = acc;
  }
  float2* P = fftM<M1, true>(sm);  // unnormalized subsampled z1 * 2048... (scale below)
  // U1_sub = |P|/2048 (exact subsample of |ifft2048(xh*psi1)|)
#pragma unroll
  for (int i = 0; i < (M1 + NTH - 1) / NTH; ++i) {
    const int m = (int)threadIdx.x + NTH * i;
    if (M1 < NTH && m >= M1) break;
    const float2 v = P[swz(m)];
    const float mg = sqrtf(v.x * v.x + v.y * v.y) * (1.0f / 2048.0f);
    sm.A[swz(m)] = make_float2(mg, 0.0f);
  }
  float2* P2 = fftM<M1, false>(sm);  // V = fft_M1(U1_sub)
  float2* dst = U1h + (size_t)n * U1H_STRIDE + u1h_off(j1);
#pragma unroll
  for (int i = 0; i < (M1 + NTH - 1) / NTH; ++i) {
    const int m = (int)threadIdx.x + NTH * i;
    if (M1 < NTH && m >= M1) break;
    dst[m] = P2[swz(m)];
  }
  const int b = n / 6, c = n % 6;
  smooth_log_out<M1>(sm, P2, out + ((size_t)b * 440 + j1) * 6 + c);
}

// Stage C: per (n, p)->(k,j1): fold(V*psi2) M1->M2, ifft_M2, |.|/M1 = U2_sub,
// direct 5-bin DFT (bins 0..4 are all that phi keeps), reconstruct+log-mean.
template <int M2>
__global__ __launch_bounds__(NTH) void kC(const float2* __restrict__ U1h,
                                          float* __restrict__ out,
                                          int p_base, int cnt) {
  __shared__ SMem sm;
  init_tw(sm);
  const int n = (int)blockIdx.x / cnt;
  const int p = p_base + (int)blockIdx.x % cnt;
  int k = 1;
  while (k < 9 && p >= 4 * k * (k + 1)) ++k;  // off(k)=4k(k-1), run length 8k
  const int j1 = p - 4 * k * (k - 1);
  const int o = j1 >> 3;
  const int M1 = (o < 3) ? (2048 >> o) : 256;
  const int F = M1 / M2;  // >= 1 always (k-1 >= o)
  const float xi = 0.4f * exp2f(-(float)k);
  const float sig = 0.8f * xi;
  const float inv2s2 = 1.0f / (2.0f * sig * sig);
  const float2* src = U1h + (size_t)n * U1H_STRIDE + u1h_off(j1);
#pragma unroll
  for (int i = 0; i < (M2 + NTH - 1) / NTH; ++i) {
    const int m = (int)threadIdx.x + NTH * i;
    if (M2 < NTH && m >= M2) break;
    float2 acc = make_float2(0.0f, 0.0f);
    for (int q = 0; q < F; ++q) {
      const int idx = m + q * M2;  // bin in [0, M1), signed within M1 period
      const float fr = (float)(idx < (M1 >> 1) ? idx : idx - M1) * (1.0f / 2048.0f);
      const float d = fr - xi;
      const float g = __expf(-d * d * inv2s2);
      const float2 v = src[idx];
      acc.x += v.x * g;
      acc.y += v.y * g;
    }
    sm.A[swz(m)] = acc;
  }
  float2* P = fftM<M2, true>(sm);
  // phase 1: u_t = |P_t|/M1; partial DFT bins 0..4
  const float invM1 = 1.0f / (float)M1;
  float b0 = 0, b1r = 0, b1i = 0, b2r = 0, b2i = 0, b3r = 0, b3i = 0, b4r = 0, b4i = 0;
#pragma unroll
  for (int i = 0; i < (M2 + NTH - 1) / NTH; ++i) {
    const int t = (int)threadIdx.x + NTH * i;
    if (M2 < NTH && t >= M2) break;
    const float2 v = P[swz(t)];
    const float u = sqrtf(v.x * v.x + v.y * v.y) * invM1;
    float sv, cv;
    __sincosf((6.283185307179586f / (float)M2) * (float)t, &sv, &cv);
    b0 += u;
    b1r += u * cv; b1i -= u * sv;
    const float c2 = cv * cv - sv * sv, s2 = 2.0f * sv * cv;
    b2r += u * c2; b2i -= u * s2;
    const float c3 = c2 * cv - s2 * sv, s3 = s2 * cv + c2 * sv;
    b3r += u * c3; b3i -= u * s3;
    const float c4 = c3 * cv - s3 * sv, s4 = s3 * cv + c3 * sv;
    b4r += u * c4; b4i -= u * s4;
  }
  b0 = wave_sum(b0);
  b1r = wave_sum(b1r); b1i = wave_sum(b1i);
  b2r = wave_sum(b2r); b2i = wave_sum(b2i);
  b3r = wave_sum(b3r); b3i = wave_sum(b3i);
  b4r = wave_sum(b4r); b4i = wave_sum(b4i);
  const int lane = (int)threadIdx.x & 63, wid = (int)threadIdx.x >> 6;
  if (lane == 0) {
    sm.binred[wid][0] = b0;
    sm.binred[wid][1] = b1r; sm.binred[wid][2] = b1i;
    sm.binred[wid][3] = b2r; sm.binred[wid][4] = b2i;
    sm.binred[wid][5] = b3r; sm.binred[wid][6] = b3i;
    sm.binred[wid][7] = b4r; sm.binred[wid][8] = b4i;
  }
  __syncthreads();
  float Bv[9];
#pragma unroll
  for (int bi = 0; bi < 9; ++bi)
    Bv[bi] = sm.binred[0][bi] + sm.binred[1][bi] + sm.binred[2][bi] + sm.binred[3][bi];
  // phase 2: s_t = (1/M2)(B0 + 2*sum phi_f Re(B_f e^{+i w f t})), mean log
  const float k1 = 2.0f * __expf(-1.220703125f);
  const float k2 = 2.0f * __expf(-4.8828125f);
  const float k3 = 2.0f * __expf(-10.986328125f);
  const float k4 = 2.0f * __expf(-19.53125f);
  const float invM2 = 1.0f / (float)M2;
  float part = 0.0f;
#pragma unroll
  for (int i = 0; i < (M2 + NTH - 1) / NTH; ++i) {
    const int t = (int)threadIdx.x + NTH * i;
    if (M2 < NTH && t >= M2) break;
    float sv, cv;
    __sincosf((6.283185307179586f / (float)M2) * (float)t, &sv, &cv);
    float acc = Bv[0] + k1 * (Bv[1] * cv - Bv[2] * sv);
    const float c2 = cv * cv - sv * sv, s2 = 2.0f * sv * cv;
    acc += k2 * (Bv[3] * c2 - Bv[4] * s2);
    const float c3 = c2 * cv - s2 * sv, s3 = s2 * cv + c2 * sv;
    acc += k3 * (Bv[5] * c3 - Bv[6] * s3);
    const float c4 = c3 * cv - s3 * sv, s4 = s3 * cv + c3 * sv;
    acc += k4 * (Bv[7] * c4 - Bv[8] * s4);
    part += __logf(acc * invM2 + 1e-6f);
  }
  part = wave_sum(part);
  if (lane == 0) sm.red[wid] = part;
  __syncthreads();
  const int b = n / 6, c = n % 6;
  if (threadIdx.x == 0)
    out[((size_t)b * 440 + 80 + p) * 6 + c] =
        (sm.red[0] + sm.red[1] + sm.red[2] + sm.red[3]) * invM2;
}

extern "C" void kernel_launch(void* const* d_in, const int* in_sizes, int n_in,
                              void* d_out, int out_size, void* d_ws, size_t ws_size,
                              hipStream_t stream) {
  (void)in_sizes; (void)n_in; (void)out_size; (void)ws_size;
  const float* x = (const float*)d_in[0];  // [8, 2048, 6] fp32
  float* out = (float*)d_out;              // [8, 440, 6] fp32
  float2* U1h = (float2*)d_ws;                                   // 16.5 MB
  float2* xh = (float2*)((char*)d_ws +
                         (size_t)48 * U1H_STRIDE * sizeof(float2));  // +786 KB
  kA<<<dim3(48), dim3(NTH), 0, stream>>>(x, xh);
  kB<2048><<<dim3(48 * 8),  dim3(NTH), 0, stream>>>(xh, U1h, out, 0, 8);
  kB<1024><<<dim3(48 * 8),  dim3(NTH), 0, stream>>>(xh, U1h, out, 8, 8);
  kB<512> <<<dim3(48 * 8),  dim3(NTH), 0, stream>>>(xh, U1h, out, 16, 8);
  kB<256> <<<dim3(48 * 56), dim3(NTH), 0, stream>>>(xh, U1h, out, 24, 56);
  kC<2048><<<dim3(48 * 8),  dim3(NTH), 0, stream>>>(U1h, out, 0, 8);    // k=1
  kC<1024><<<dim3(48 * 16), dim3(NTH), 0, stream>>>(U1h, out, 8, 16);   // k=2
  kC<512> <<<dim3(48 * 24), dim3(NTH), 0, stream>>>(U1h, out, 24, 24);  // k=3
  kC<256> <<<dim3(48 * 312), dim3(NTH), 0, stream>>>(U1h, out, 48, 312); // k>=4
}

// Round 3
// 128.173 us; speedup vs baseline: 2.2064x; 1.5099x over previous
//
#include <hip/hip_runtime.h>

#define NTH 256
#define U1H_STRIDE 43008  // per-signal float2s: 8*2048 + 8*1024 + 8*512 + 56*256

// LDS: 16384+16384+4096+16+112 = 36992 B -> 4 blocks/CU.
struct SMem {
  float2 A[2048];
  float2 B[2048];
  float2 tw[512];     // contiguous per-M table, M/4 entries used
  float red[4];
  float binred[4][7];
};

// Bank swizzle (verified conflict-free for all stage patterns incl. per-wave).
__device__ __forceinline__ int swz(int i) { return i ^ (((i >> 4) & 3) * 5); }

__device__ __forceinline__ float2 cmul(float2 a, float2 b) {
  return make_float2(a.x * b.x - a.y * b.y, a.x * b.y + a.y * b.x);
}

// Butterfly xor-reduce: every lane ends with the full 64-lane sum.
__device__ __forceinline__ float wsum(float v) {
#pragma unroll
  for (int off = 1; off < 64; off <<= 1) v += __shfl_xor(v, off, 64);
  return v;
}

// tw[u] = e^{-2*pi*i*u/M}, u in [0, M/4). Visibility covered by fft's leading barrier.
template <int M>
__device__ __forceinline__ void init_twM(SMem& sm) {
  constexpr int NE = M / 4;
#pragma unroll
  for (int i = 0; i < (NE + NTH - 1) / NTH; ++i) {
    const int u = (int)threadIdx.x + NTH * i;
    if (NE < NTH && u >= NE) break;
    float s, c;
    sincosf(-(6.283185307179586f / (float)M) * (float)u, &s, &c);
    sm.tw[u] = make_float2(c, s);
  }
}

template <bool INV>
__device__ __forceinline__ void bfly4(float2* cur, float2* oth, const float2* tw,
                                      int j, int logs, int NQ) {
  const int s = 1 << logs;
  const float2 a = cur[swz(j)];
  const float2 b = cur[swz(j + NQ)];
  const float2 c = cur[swz(j + 2 * NQ)];
  const float2 d = cur[swz(j + 3 * NQ)];
  float2 w1 = tw[j & ~(s - 1)];
  if (INV) w1.y = -w1.y;
  const float2 w2 = cmul(w1, w1);
  const float2 w3 = cmul(w2, w1);
  const float t0x = a.x + c.x, t0y = a.y + c.y;
  const float t1x = a.x - c.x, t1y = a.y - c.y;
  const float t2x = b.x + d.x, t2y = b.y + d.y;
  const float bdx = b.x - d.x, bdy = b.y - d.y;
  const float sgn = INV ? -1.0f : 1.0f;
  const float t3x = sgn * bdy, t3y = -sgn * bdx;  // -i*(b-d) fwd, +i inv
  const int wb = (j & (s - 1)) + ((j >> logs) << (logs + 2));
  oth[swz(wb)]         = make_float2(t0x + t2x, t0y + t2y);
  oth[swz(wb + s)]     = cmul(w1, make_float2(t1x + t3x, t1y + t3y));
  oth[swz(wb + 2 * s)] = cmul(w2, make_float2(t0x - t2x, t0y - t2y));
  oth[swz(wb + 3 * s)] = cmul(w3, make_float2(t1x - t3x, t1y - t3y));
}

// Block-wide FFT, M in {1024, 2048}: NQ >= 256 so all threads are busy.
template <int M, bool INV>
__device__ __forceinline__ float2* bfft(SMem& sm) {
  constexpr int NQ = M / 4;
  float2* cur = sm.A;
  float2* oth = sm.B;
#pragma unroll
  for (int st = 0; st < 5; ++st) {  // 4^5 = 1024
    const int logs = 2 * st;
    __syncthreads();
#pragma unroll
    for (int i = 0; i < NQ / NTH; ++i)
      bfly4<INV>(cur, oth, sm.tw, (int)threadIdx.x + NTH * i, logs, NQ);
    float2* t = cur; cur = oth; oth = t;
  }
  if (M == 2048) {
    __syncthreads();
#pragma unroll
    for (int i = 0; i < M / (2 * NTH); ++i) {
      const int j = (int)threadIdx.x + NTH * i;
      const float2 a = cur[swz(j)];
      const float2 b = cur[swz(j + M / 2)];
      oth[swz(j)]         = make_float2(a.x + b.x, a.y + b.y);
      oth[swz(j + M / 2)] = make_float2(a.x - b.x, a.y - b.y);
    }
    float2* t = cur; cur = oth; oth = t;
  }
  __syncthreads();
  return cur;
}

// Per-wave FFT, M in {256, 512}: wave-local buffers (Aw/Bw pre-offset), lane l.
// All 4 waves of the block run symmetric paths -> barriers are cheap & uniform.
template <int M, bool INV>
__device__ __forceinline__ float2* wfft(float2* Aw, float2* Bw, const float2* tw, int l) {
  constexpr int NQ = M / 4;  // 64 or 128
  float2* cur = Aw;
  float2* oth = Bw;
#pragma unroll
  for (int st = 0; st < 4; ++st) {  // 4^4 = 256
    const int logs = 2 * st;
    __syncthreads();
#pragma unroll
    for (int i = 0; i < NQ / 64; ++i) bfly4<INV>(cur, oth, tw, l + 64 * i, logs, NQ);
    float2* t = cur; cur = oth; oth = t;
  }
  if (M == 512) {
    __syncthreads();
#pragma unroll
    for (int i = 0; i < M / 128; ++i) {
      const int j = l + 64 * i;
      const float2 a = cur[swz(j)];
      const float2 b = cur[swz(j + M / 2)];
      oth[swz(j)]         = make_float2(a.x + b.x, a.y + b.y);
      oth[swz(j + M / 2)] = make_float2(a.x - b.x, a.y - b.y);
    }
    float2* t = cur; cur = oth; oth = t;
  }
  __syncthreads();
  return cur;
}

__device__ __forceinline__ int u1h_off(int j1) {
  const int o = j1 >> 3;
  if (o == 0) return j1 * 2048;
  if (o == 1) return 16384 + (j1 - 8) * 1024;
  if (o == 2) return 24576 + (j1 - 16) * 512;
  return 28672 + (j1 - 24) * 256;
}

#define PHI1 0.29504296f    // e^{-1.220703125}
#define PHI2 0.0075683594f  // e^{-4.8828125}
#define PHI3 1.6944313e-5f  // e^{-10.986328125}

// ---------------- Stage A ----------------
__global__ __launch_bounds__(NTH) void kA(const float* __restrict__ x,
                                          float2* __restrict__ xh) {
  __shared__ SMem sm;
  init_twM<2048>(sm);
  const int n = blockIdx.x, b = n / 6, c = n % 6;
  const float* xp = x + (size_t)b * (2048 * 6) + c;
#pragma unroll
  for (int i = 0; i < 8; ++i) {
    const int t = (int)threadIdx.x + NTH * i;
    sm.A[swz(t)] = make_float2(xp[t * 6], 0.0f);
  }
  float2* P = bfft<2048, false>(sm);
#pragma unroll
  for (int i = 0; i < 8; ++i) {
    const int t = (int)threadIdx.x + NTH * i;
    xh[(size_t)n * 2048 + t] = P[swz(t)];
  }
}

// ---------------- Stage B bodies ----------------
template <int M1>
__device__ __forceinline__ void kB_block(SMem& sm, const float2* __restrict__ src,
                                         float2* __restrict__ U1h, float* __restrict__ out,
                                         int n, int b, int c, int j1) {
  init_twM<M1>(sm);
  constexpr int F = 2048 / M1;
  const float xi = 0.4f * exp2f(-0.125f * (float)j1);
  const float sig = 0.1f * xi;
  const float inv2s2 = 1.0f / (2.0f * sig * sig);
#pragma unroll
  for (int i = 0; i < M1 / NTH; ++i) {
    const int m = (int)threadIdx.x + NTH * i;
    float2 acc = make_float2(0.0f, 0.0f);
#pragma unroll
    for (int q = 0; q < F; ++q) {
      const int f = m + q * M1;
      const float fr = (float)(f < 1024 ? f : f - 2048) * (1.0f / 2048.0f);
      const float d = fr - xi;
      const float g = __expf(-d * d * inv2s2);
      const float2 v = src[f];
      acc.x += v.x * g; acc.y += v.y * g;
    }
    sm.A[swz(m)] = acc;
  }
  float2* P = bfft<M1, true>(sm);
#pragma unroll
  for (int i = 0; i < M1 / NTH; ++i) {
    const int m = (int)threadIdx.x + NTH * i;
    const float2 v = P[swz(m)];
    sm.A[swz(m)] = make_float2(sqrtf(v.x * v.x + v.y * v.y) * (1.0f / 2048.0f), 0.0f);
  }
  float2* P2 = bfft<M1, false>(sm);
  float2* dst = U1h + (size_t)n * U1H_STRIDE + u1h_off(j1);
#pragma unroll
  for (int i = 0; i < M1 / NTH; ++i) {
    const int m = (int)threadIdx.x + NTH * i;
    dst[m] = P2[swz(m)];
  }
  const float invM = 1.0f / (float)M1;
  const float c0 = P2[0].x * invM;
  const float2 U1 = P2[1], U2 = P2[2], U3 = P2[3];
  const float k1 = PHI1 * 2.0f * invM, k2 = PHI2 * 2.0f * invM, k3 = PHI3 * 2.0f * invM;
  float part = 0.0f;
#pragma unroll
  for (int i = 0; i < M1 / NTH; ++i) {
    const int t = (int)threadIdx.x + NTH * i;
    float sv, cv;
    __sincosf((6.283185307179586f / (float)M1) * (float)t, &sv, &cv);
    float acc = c0 + k1 * (U1.x * cv - U1.y * sv);
    const float c2 = cv * cv - sv * sv, s2 = 2.0f * sv * cv;
    acc += k2 * (U2.x * c2 - U2.y * s2);
    const float c3 = c2 * cv - s2 * sv, s3 = s2 * cv + c2 * sv;
    acc += k3 * (U3.x * c3 - U3.y * s3);
    part += __logf(acc + 1e-6f);
  }
  part = wsum(part);
  const int lane = (int)threadIdx.x & 63, wid = (int)threadIdx.x >> 6;
  if (lane == 0) sm.red[wid] = part;
  __syncthreads();
  if (threadIdx.x == 0)
    out[((size_t)b * 440 + j1) * 6 + c] =
        (sm.red[0] + sm.red[1] + sm.red[2] + sm.red[3]) * invM;
}

template <int M1>
__device__ __forceinline__ void kB_wave(SMem& sm, const float2* __restrict__ src,
                                        float2* __restrict__ U1h, float* __restrict__ out,
                                        int n, int b, int c, int j1base) {
  init_twM<M1>(sm);
  const int l = (int)threadIdx.x & 63, wid = (int)threadIdx.x >> 6;
  const int j1 = j1base + wid;
  float2* Aw = sm.A + wid * M1;
  float2* Bw = sm.B + wid * M1;
  constexpr int F = 2048 / M1;
  const float xi = 0.4f * exp2f(-0.125f * (float)j1);
  const float sig = 0.1f * xi;
  const float inv2s2 = 1.0f / (2.0f * sig * sig);
#pragma unroll
  for (int i = 0; i < M1 / 64; ++i) {
    const int m = l + 64 * i;
    float2 acc = make_float2(0.0f, 0.0f);
#pragma unroll
    for (int q = 0; q < F; ++q) {
      const int f = m + q * M1;
      const float fr = (float)(f < 1024 ? f : f - 2048) * (1.0f / 2048.0f);
      const float d = fr - xi;
      const float g = __expf(-d * d * inv2s2);
      const float2 v = src[f];
      acc.x += v.x * g; acc.y += v.y * g;
    }
    Aw[swz(m)] = acc;
  }
  float2* P = wfft<M1, true>(Aw, Bw, sm.tw, l);
#pragma unroll
  for (int i = 0; i < M1 / 64; ++i) {
    const int m = l + 64 * i;
    const float2 v = P[swz(m)];
    Aw[swz(m)] = make_float2(sqrtf(v.x * v.x + v.y * v.y) * (1.0f / 2048.0f), 0.0f);
  }
  float2* P2 = wfft<M1, false>(Aw, Bw, sm.tw, l);
  float2* dst = U1h + (size_t)n * U1H_STRIDE + u1h_off(j1);
#pragma unroll
  for (int i = 0; i < M1 / 64; ++i) {
    const int m = l + 64 * i;
    dst[m] = P2[swz(m)];
  }
  const float invM = 1.0f / (float)M1;
  const float c0 = P2[0].x * invM;
  const float2 U1 = P2[1], U2 = P2[2], U3 = P2[3];
  const float k1 = PHI1 * 2.0f * invM, k2 = PHI2 * 2.0f * invM, k3 = PHI3 * 2.0f * invM;
  float part = 0.0f;
#pragma unroll
  for (int i = 0; i < M1 / 64; ++i) {
    const int t = l + 64 * i;
    float sv, cv;
    __sincosf((6.283185307179586f / (float)M1) * (float)t, &sv, &cv);
    float acc = c0 + k1 * (U1.x * cv - U1.y * sv);
    const float c2 = cv * cv - sv * sv, s2 = 2.0f * sv * cv;
    acc += k2 * (U2.x * c2 - U2.y * s2);
    const float c3 = c2 * cv - s2 * sv, s3 = s2 * cv + c2 * sv;
    acc += k3 * (U3.x * c3 - U3.y * s3);
    part += __logf(acc + 1e-6f);
  }
  part = wsum(part);
  if (l == 0) out[((size_t)b * 440 + j1) * 6 + c] = part * invM;
}

// kB_all: 32 blocks per signal: [0,8) M=2048; [8,16) M=1024; [16,18) M=512 (x4
// paths/block); [18,32) M=256 (x4).
__global__ __launch_bounds__(NTH, 4) void kB_all(const float2* __restrict__ xh,
                                                 float2* __restrict__ U1h,
                                                 float* __restrict__ out) {
  __shared__ SMem sm;
  const int n = (int)blockIdx.x >> 5;
  const int lc = (int)blockIdx.x & 31;
  const int b = n / 6, c = n % 6;
  const float2* src = xh + (size_t)n * 2048;
  if (lc < 8)       kB_block<2048>(sm, src, U1h, out, n, b, c, lc);
  else if (lc < 16) kB_block<1024>(sm, src, U1h, out, n, b, c, lc);
  else if (lc < 18) kB_wave<512>(sm, src, U1h, out, n, b, c, 16 + 4 * (lc - 16));
  else              kB_wave<256>(sm, src, U1h, out, n, b, c, 24 + 4 * (lc - 18));
}

// ---------------- Stage C bodies ----------------
template <int M2>
__device__ __forceinline__ void kC_block(SMem& sm, const float2* __restrict__ V,
                                         float* __restrict__ outp, int M1, int F, float xi) {
  init_twM<M2>(sm);
  const float sig = 0.8f * xi;
  const float inv2s2 = 1.0f / (2.0f * sig * sig);
#pragma unroll
  for (int i = 0; i < M2 / NTH; ++i) {
    const int m = (int)threadIdx.x + NTH * i;
    float2 acc = make_float2(0.0f, 0.0f);
    for (int q = 0; q < F; ++q) {
      const int idx = m + q * M2;
      const float fr = (float)(idx < (M1 >> 1) ? idx : idx - M1) * (1.0f / 2048.0f);
      const float d = fr - xi;
      const float g = __expf(-d * d * inv2s2);
      const float2 v = V[idx];
      acc.x += v.x * g; acc.y += v.y * g;
    }
    sm.A[swz(m)] = acc;
  }
  float2* P = bfft<M2, true>(sm);
  const float invM1 = 1.0f / (float)M1;
  float cvs[M2 / NTH], svs[M2 / NTH];
  float b0 = 0, b1r = 0, b1i = 0, b2r = 0, b2i = 0, b3r = 0, b3i = 0;
#pragma unroll
  for (int i = 0; i < M2 / NTH; ++i) {
    const int t = (int)threadIdx.x + NTH * i;
    const float2 v = P[swz(t)];
    const float u = sqrtf(v.x * v.x + v.y * v.y) * invM1;
    float sv, cv;
    __sincosf((6.283185307179586f / (float)M2) * (float)t, &sv, &cv);
    cvs[i] = cv; svs[i] = sv;
    b0 += u;
    b1r += u * cv; b1i -= u * sv;
    const float c2 = cv * cv - sv * sv, s2 = 2.0f * sv * cv;
    b2r += u * c2; b2i -= u * s2;
    const float c3 = c2 * cv - s2 * sv, s3 = s2 * cv + c2 * sv;
    b3r += u * c3; b3i -= u * s3;
  }
  b0 = wsum(b0);
  b1r = wsum(b1r); b1i = wsum(b1i);
  b2r = wsum(b2r); b2i = wsum(b2i);
  b3r = wsum(b3r); b3i = wsum(b3i);
  const int lane = (int)threadIdx.x & 63, wid = (int)threadIdx.x >> 6;
  if (lane == 0) {
    sm.binred[wid][0] = b0;
    sm.binred[wid][1] = b1r; sm.binred[wid][2] = b1i;
    sm.binred[wid][3] = b2r; sm.binred[wid][4] = b2i;
    sm.binred[wid][5] = b3r; sm.binred[wid][6] = b3i;
  }
  __syncthreads();
  float Bv[7];
#pragma unroll
  for (int bi = 0; bi < 7; ++bi)
    Bv[bi] = sm.binred[0][bi] + sm.binred[1][bi] + sm.binred[2][bi] + sm.binred[3][bi];
  const float k1 = 2.0f * PHI1, k2 = 2.0f * PHI2, k3 = 2.0f * PHI3;
  const float invM2 = 1.0f / (float)M2;
  float part = 0.0f;
#pragma unroll
  for (int i = 0; i < M2 / NTH; ++i) {
    const float cv = cvs[i], sv = svs[i];
    float acc = Bv[0] + k1 * (Bv[1] * cv - Bv[2] * sv);
    const float c2 = cv * cv - sv * sv, s2 = 2.0f * sv * cv;
    acc += k2 * (Bv[3] * c2 - Bv[4] * s2);
    const float c3 = c2 * cv - s2 * sv, s3 = s2 * cv + c2 * sv;
    acc += k3 * (Bv[5] * c3 - Bv[6] * s3);
    part += __logf(acc * invM2 + 1e-6f);
  }
  part = wsum(part);
  if (lane == 0) sm.red[wid] = part;
  __syncthreads();
  if (threadIdx.x == 0)
    *outp = (sm.red[0] + sm.red[1] + sm.red[2] + sm.red[3]) * invM2;
}

template <int M2>
__device__ __forceinline__ void kC_wave(SMem& sm, const float2* __restrict__ V,
                                        float* __restrict__ outp, int M1, int F, float xi) {
  init_twM<M2>(sm);
  const int l = (int)threadIdx.x & 63, wid = (int)threadIdx.x >> 6;
  float2* Aw = sm.A + wid * M2;
  float2* Bw = sm.B + wid * M2;
  const float sig = 0.8f * xi;
  const float inv2s2 = 1.0f / (2.0f * sig * sig);
#pragma unroll
  for (int i = 0; i < M2 / 64; ++i) {
    const int m = l + 64 * i;
    float2 acc = make_float2(0.0f, 0.0f);
    for (int q = 0; q < F; ++q) {
      const int idx = m + q * M2;
      const float fr = (float)(idx < (M1 >> 1) ? idx : idx - M1) * (1.0f / 2048.0f);
      const float d = fr - xi;
      const float g = __expf(-d * d * inv2s2);
      const float2 v = V[idx];
      acc.x += v.x * g; acc.y += v.y * g;
    }
    Aw[swz(m)] = acc;
  }
  float2* P = wfft<M2, true>(Aw, Bw, sm.tw, l);
  const float invM1 = 1.0f / (float)M1;
  float cvs[M2 / 64], svs[M2 / 64];
  float b0 = 0, b1r = 0, b1i = 0, b2r = 0, b2i = 0, b3r = 0, b3i = 0;
#pragma unroll
  for (int i = 0; i < M2 / 64; ++i) {
    const int t = l + 64 * i;
    const float2 v = P[swz(t)];
    const float u = sqrtf(v.x * v.x + v.y * v.y) * invM1;
    float sv, cv;
    __sincosf((6.283185307179586f / (float)M2) * (float)t, &sv, &cv);
    cvs[i] = cv; svs[i] = sv;
    b0 += u;
    b1r += u * cv; b1i -= u * sv;
    const float c2 = cv * cv - sv * sv, s2 = 2.0f * sv * cv;
    b2r += u * c2; b2i -= u * s2;
    const float c3 = c2 * cv - s2 * sv, s3 = s2 * cv + c2 * sv;
    b3r += u * c3; b3i -= u * s3;
  }
  b0 = wsum(b0);
  b1r = wsum(b1r); b1i = wsum(b1i);
  b2r = wsum(b2r); b2i = wsum(b2i);
  b3r = wsum(b3r); b3i = wsum(b3i);
  const float k1 = 2.0f * PHI1, k2 = 2.0f * PHI2, k3 = 2.0f * PHI3;
  const float invM2 = 1.0f / (float)M2;
  float part = 0.0f;
#pragma unroll
  for (int i = 0; i < M2 / 64; ++i) {
    const float cv = cvs[i], sv = svs[i];
    float acc = b0 + k1 * (b1r * cv - b1i * sv);
    const float c2 = cv * cv - sv * sv, s2 = 2.0f * sv * cv;
    acc += k2 * (b2r * c2 - b2i * s2);
    const float c3 = c2 * cv - s2 * sv, s3 = s2 * cv + c2 * sv;
    acc += k3 * (b3r * c3 - b3i * s3);
    part += __logf(acc * invM2 + 1e-6f);
  }
  part = wsum(part);
  if (l == 0) *outp = part * invM2;
}

// kC_all: 108 blocks per signal:
//  [0,8):   k=1, M2=2048, j1=lc          (block-wide)
//  [8,24):  k=2, M2=1024, j1=lc-8        (block-wide)
//  [24,30): k=3, M2=512,  j1=4g+wid      (per-wave, g=lc-24)
//  [30,108): k in 4..9, M2=256, grouped 4 paths of same (k, octave) per block.
__global__ __launch_bounds__(NTH, 4) void kC_all(const float2* __restrict__ U1h,
                                                 float* __restrict__ out) {
  __shared__ SMem sm;
  const int n = (int)blockIdx.x / 108;
  const int lc = (int)blockIdx.x % 108;
  const int b = n / 6, c = n % 6;
  const float2* base = U1h + (size_t)n * U1H_STRIDE;
  const int wid = (int)threadIdx.x >> 6;
  if (lc < 8) {
    const int j1 = lc, k = 1;
    const float xi = 0.4f * exp2f(-(float)k);
    const int p = 4 * k * (k - 1) + j1;
    kC_block<2048>(sm, base + u1h_off(j1), out + ((size_t)b * 440 + 80 + p) * 6 + c,
                   2048, 1, xi);
  } else if (lc < 24) {
    const int j1 = lc - 8, k = 2;
    const int o = j1 >> 3;
    const int M1 = 2048 >> o;
    const float xi = 0.4f * exp2f(-(float)k);
    const int p = 4 * k * (k - 1) + j1;
    kC_block<1024>(sm, base + u1h_off(j1), out + ((size_t)b * 440 + 80 + p) * 6 + c,
                   M1, M1 / 1024, xi);
  } else if (lc < 30) {
    const int g = lc - 24, k = 3;
    const int j1 = 4 * g + wid;
    const int o = j1 >> 3;
    const int M1 = 2048 >> o;
    const float xi = 0.4f * exp2f(-(float)k);
    const int p = 4 * k * (k - 1) + j1;
    kC_wave<512>(sm, base + u1h_off(j1), out + ((size_t)b * 440 + 80 + p) * 6 + c,
                 M1, M1 / 512, xi);
  } else {
    int bc = lc - 30;  // [0,78): k=4 has 8 groups, k=5:10, ... k=9:18
    int k = 4;
    while (bc >= 2 * k) { bc -= 2 * k; ++k; }
    const int j1 = 4 * bc + wid;
    const int o = j1 >> 3;
    const int M1 = (o < 3) ? (2048 >> o) : 256;
    const float xi = 0.4f * exp2f(-(float)k);
    const int p = 4 * k * (k - 1) + j1;
    kC_wave<256>(sm, base + u1h_off(j1), out + ((size_t)b * 440 + 80 + p) * 6 + c,
                 M1, M1 / 256, xi);
  }
}

extern "C" void kernel_launch(void* const* d_in, const int* in_sizes, int n_in,
                              void* d_out, int out_size, void* d_ws, size_t ws_size,
                              hipStream_t stream) {
  (void)in_sizes; (void)n_in; (void)out_size; (void)ws_size;
  const float* x = (const float*)d_in[0];  // [8, 2048, 6] fp32
  float* out = (float*)d_out;              // [8, 440, 6] fp32
  float2* U1h = (float2*)d_ws;                                       // 16.5 MB
  float2* xh = (float2*)((char*)d_ws + (size_t)48 * U1H_STRIDE * sizeof(float2));
  kA<<<dim3(48), dim3(NTH), 0, stream>>>(x, xh);
  kB_all<<<dim3(48 * 32), dim3(NTH), 0, stream>>>(xh, U1h, out);
  kC_all<<<dim3(48 * 108), dim3(NTH), 0, stream>>>(U1h, out);
}